// Round 21
// baseline (185.303 us; speedup 1.0000x reference)
//
#include <hip/hip_runtime.h>
#include <hip/hip_bf16.h>
#include <math.h>

#define B_    500
#define T_    100
#define I_    700
#define HALF_ 350
#define H_    512
#define O_    20
#define M_    (B_*T_)     // 50000
#define BH_   (B_*H_)     // 256000
#define TP_   112         // T padded
#define KP_   352         // padded K per phase (weights)
#define ASTR_ 712         // A LDS row stride shorts (1424B = 356 dw, mod32=4: conflict-free)
#define DRS_  116         // dr stride bytes per h row (29 dw: 2-way scan reads)
#define NB_   12500       // out_loss blocks

#define START_T  10
#define CODING_T 10
#define REMAIN_T 5

typedef __attribute__((ext_vector_type(8))) short short8v;
typedef __attribute__((ext_vector_type(8))) unsigned short ushort8v;
typedef __attribute__((ext_vector_type(4))) float f32x4;
typedef __attribute__((ext_vector_type(2))) float f32x2;

__device__ __forceinline__ float sigmoidf_(float x) {
  return 1.0f / (1.0f + expf(-x));
}

__device__ __forceinline__ unsigned cvtpk(float lo, float hi) {
  unsigned r;
  asm("v_cvt_pk_bf16_f32 %0, %1, %2" : "=v"(r) : "v"(lo), "v"(hi));
  return r;
}

__device__ __forceinline__ unsigned cvtpk_fp8x4(float f0, float f1, float f2, float f3) {
  int r = __builtin_amdgcn_cvt_pk_fp8_f32(f0, f1, 0, false);
  r = __builtin_amdgcn_cvt_pk_fp8_f32(f2, f3, r, true);
  return (unsigned)r;
}

__device__ __forceinline__ unsigned short f2bf(float f) {
  unsigned u = __float_as_uint(f);
  u = (u + 0x7fffu + ((u >> 16) & 1u)) >> 16;   // RTNE
  return (unsigned short)u;
}

// ---------- convert weights fp32 -> padded bf16 Wb[2][512][352] ----------
// phase 0: kk<350 -> W1[kk], else 0
// phase 1: kk>=2  -> W2[kk-2], else 0   (A col window base 348)
__global__ __launch_bounds__(256) void convert_w(
    const float* __restrict__ W1, const float* __restrict__ W2,
    unsigned short* __restrict__ wb)
{
  const int idx = blockIdx.x * 256 + threadIdx.x;
  const int ph  = idx / (H_ * (KP_ / 8));
  const int rem = idx % (H_ * (KP_ / 8));
  const int h   = rem / (KP_ / 8);
  const int cc  = (rem % (KP_ / 8)) * 8;
  ushort8v v;
#pragma unroll
  for (int j = 0; j < 8; ++j) {
    const int kk = cc + j;
    float f;
    if (ph == 0) f = (kk < HALF_) ? W1[(size_t)h * HALF_ + kk] : 0.0f;
    else         f = (kk >= 2)    ? W2[(size_t)h * HALF_ + kk - 2] : 0.0f;
    v[j] = f2bf(f);
  }
  *reinterpret_cast<ushort8v*>(wb + (((size_t)ph * H_ + h) * KP_) + cc) = v;
}

// ---------- GEMM: full A resident in LDS, barrier-free free-running waves ----
// As cols 0..351 = input[0..351]; cols 352..703 = input[348..699].
// Window k (0..21): As col base k*32. dr -> global fp8 [b][ph][h][116].
__global__ __launch_bounds__(1024, 4) void drive_gemm(
    const float* __restrict__ input, const unsigned short* __restrict__ Wb,
    unsigned char* __restrict__ drg)
{
  __shared__ __align__(16) unsigned short As[TP_ * ASTR_];   // 159488 B

  const int tid  = threadIdx.x;
  const int lane = tid & 63;
  const int w    = tid >> 6;           // 0..15
  const int b    = blockIdx.x;

  // ---- stage all of A (once): thread = (row sr, 88-col slab) ----
  {
    const int sr0 = tid >> 3;              // 0..127
    if (sr0 < TP_) {
      const int sr = (sr0 < T_) ? sr0 : (T_ - 1);   // pad rows dup row 99 (ignored later)
      const int sc = (tid & 7) * 88;                // slab start (As cols)
      const float* src = input + ((size_t)b * T_ + sr) * I_ + (sc < 352 ? sc : sc - 4);
      unsigned short* dst = As + sr0 * ASTR_ + sc;
#pragma unroll
      for (int q = 0; q < 11; ++q) {
        const float4 x0 = *(const float4*)(src + q * 8);
        const float4 x1 = *(const float4*)(src + q * 8 + 4);
        const uint4 p = {cvtpk(x0.x, x0.y), cvtpk(x0.z, x0.w),
                         cvtpk(x1.x, x1.y), cvtpk(x1.z, x1.w)};
        *(uint4*)(dst + q * 8) = p;
      }
    }
  }
  __syncthreads();   // the ONLY barrier

  // B fragment addressing (direct global; Wb L2-resident)
  const int brow = w * 32 + (lane & 15);
  const int kcS  = (lane >> 4) * 8;
  const unsigned short* bBase0 = Wb + (size_t)brow * KP_ + kcS;
  const unsigned short* bBase1 = Wb + (size_t)(brow + 16) * KP_ + kcS;
  const int arow = lane & 15;
  const int rot  = w % 11;             // per-wave window rotation (stagger)

#pragma unroll 1
  for (int ph = 0; ph < 2; ++ph) {
    f32x4 acc[7][2];
#pragma unroll
    for (int i = 0; i < 7; ++i) {
      acc[i][0] = f32x4{0.f, 0.f, 0.f, 0.f};
      acc[i][1] = f32x4{0.f, 0.f, 0.f, 0.f};
    }
    const size_t bph = (size_t)ph * H_ * KP_;

    int kw = rot;                                  // window within phase 0..10
    short8v bC0 = *reinterpret_cast<const short8v*>(bBase0 + bph + kw * 32);
    short8v bC1 = *reinterpret_cast<const short8v*>(bBase1 + bph + kw * 32);

#pragma unroll 1
    for (int kk = 0; kk < 11; ++kk) {
      const int kwn = (kw == 10) ? 0 : kw + 1;
      short8v bN0, bN1;
      if (kk < 10) {
        bN0 = *reinterpret_cast<const short8v*>(bBase0 + bph + kwn * 32);
        bN1 = *reinterpret_cast<const short8v*>(bBase1 + bph + kwn * 32);
      }
      const int cb = (ph * 11 + kw) * 32;          // As col base (shorts)
#pragma unroll
      for (int i = 0; i < 7; ++i) {
        const short8v a = *reinterpret_cast<const short8v*>(
            As + (arow + i * 16) * ASTR_ + cb + kcS);
        acc[i][0] = __builtin_amdgcn_mfma_f32_16x16x32_bf16(a, bC0, acc[i][0], 0, 0, 0);
        acc[i][1] = __builtin_amdgcn_mfma_f32_16x16x32_bf16(a, bC1, acc[i][1], 0, 0, 0);
      }
      bC0 = bN0; bC1 = bN1;
      kw = kwn;
    }

    // dump phase acc -> global fp8 (own data, no sync)
    unsigned char* ds = drg + ((size_t)(b * 2 + ph) * H_) * DRS_;
#pragma unroll
    for (int i = 0; i < 7; ++i) {
      const int tb = i * 16 + ((lane >> 4) << 2);
#pragma unroll
      for (int j = 0; j < 2; ++j) {
        const int hl = w * 32 + j * 16 + (lane & 15);
        const unsigned r =
            cvtpk_fp8x4(acc[i][j][0], acc[i][j][1], acc[i][j][2], acc[i][j][3]);
        *(unsigned*)(ds + (size_t)hl * DRS_ + tb) = r;
      }
    }
  }
}

// ---------- scan: per-b LIF from global fp8 dr (LDS-staged) -> ballot spikes --
__global__ __launch_bounds__(512) void scan_kernel(
    const unsigned char* __restrict__ drg, const float* __restrict__ v_init,
    const float* __restrict__ tau_n, const float* __restrict__ tau_m,
    unsigned long long* __restrict__ spkw)
{
  __shared__ __align__(16) unsigned char dls[2 * H_ * DRS_];   // 118784 B

  const int tid  = threadIdx.x;
  const int lane = tid & 63;
  const int w    = tid >> 6;           // 0..7 (= h>>6)
  const int b    = blockIdx.x;

  // stage both phase planes, linear coalesced (7424 uint4)
  {
    const uint4* src = (const uint4*)(drg + (size_t)(b * 2) * H_ * DRS_);
    uint4* dst = (uint4*)dls;
#pragma unroll 1
    for (int i = tid; i < (2 * H_ * DRS_) / 16; i += 512) dst[i] = src[i];
  }
  __syncthreads();

  const int hg = tid;                  // 0..511
  const float beta1 = sigmoidf_(tau_n[hg]);
  const float beta2 = sigmoidf_(tau_n[H_ + hg]);
  const float alpha = sigmoidf_(tau_m[hg]);
  const float ob1 = 1.0f - beta1, ob2 = 1.0f - beta2, oa = 1.0f - alpha;

  float d1 = 0.0f, d2 = 0.0f, s = 0.0f;
  float v = v_init[(size_t)b * H_ + hg];
  const unsigned char* r1 = dls + (size_t)hg * DRS_;
  const unsigned char* r2 = dls + (size_t)(H_ + hg) * DRS_;
  unsigned long long* sw = spkw + (size_t)b * T_ * 8 + w;
#pragma unroll 1
  for (int c = 0; c < 25; ++c) {                    // 25 x 4 = 100 steps
    const unsigned u1 = *(const unsigned*)(r1 + c * 4);
    const unsigned u2 = *(const unsigned*)(r2 + c * 4);
    const f32x2 a1 = __builtin_amdgcn_cvt_pk_f32_fp8((int)u1, false);
    const f32x2 b1 = __builtin_amdgcn_cvt_pk_f32_fp8((int)u1, true);
    const f32x2 a2 = __builtin_amdgcn_cvt_pk_f32_fp8((int)u2, false);
    const f32x2 b2 = __builtin_amdgcn_cvt_pk_f32_fp8((int)u2, true);
    const float f1[4] = {a1[0], a1[1], b1[0], b1[1]};
    const float f2[4] = {a2[0], a2[1], b2[0], b2[1]};
#pragma unroll
    for (int j = 0; j < 4; ++j) {
      d1 = beta1 * d1 + ob1 * f1[j];
      d2 = beta2 * d2 + ob2 * f2[j];
      v = alpha * v + oa * (d1 + d2) - s;   // V_TH = 1
      const bool spk = (v > 1.0f);
      s = spk ? 1.0f : 0.0f;
      const unsigned long long mball = __ballot(spk);
      if (lane == 0) sw[(size_t)(c * 4 + j) * 8] = mball;
    }
  }
}

// ---------- output GEMM + loss: wave per (b,t), 12500 blocks ----------
__global__ __launch_bounds__(256) void out_loss(
    const unsigned long long* __restrict__ spkw, const float* __restrict__ Wout,
    const float* __restrict__ bout, const int* __restrict__ target,
    float* __restrict__ oh, float* __restrict__ partials)
{
  const int lane = threadIdx.x & 63;
  const int widx = threadIdx.x >> 6;
  const int bt = blockIdx.x * 4 + widx;          // == b*T_ + t
  const int t = bt % T_;

  const unsigned char* row = (const unsigned char*)(spkw + (size_t)bt * 8);
  const unsigned sbyte = row[lane];

  float acc[O_];
#pragma unroll
  for (int o = 0; o < O_; ++o) acc[o] = 0.0f;

#pragma unroll
  for (int j = 0; j < 8; ++j) {
    if ((sbyte >> j) & 1u) {
      const int hh = lane * 8 + j;
#pragma unroll
      for (int o = 0; o < O_; ++o) acc[o] += Wout[o * H_ + hh];
    }
  }
#pragma unroll
  for (int o = 0; o < O_; ++o) {
#pragma unroll
    for (int off = 32; off; off >>= 1) acc[o] += __shfl_xor(acc[o], off);
    acc[o] += bout[o];
  }
  if (lane < O_) oh[(size_t)bt * O_ + lane] = acc[lane];

  __shared__ float sl[4], sc[4];
  float lossc = 0.0f, corr = 0.0f;
  const bool maskv = (t > START_T) && (((t - START_T) % (CODING_T + REMAIN_T)) > REMAIN_T);
  if (maskv) {
    const int tgt = target[bt];
    float m = acc[0];
    int pred = 0;
#pragma unroll
    for (int o = 1; o < O_; ++o) { if (acc[o] > m) { m = acc[o]; pred = o; } }
    float S = 0.0f, etgt = 0.0f;
#pragma unroll
    for (int o = 0; o < O_; ++o) {
      const float eo = expf(acc[o] - m);
      S += eo;
      if (o == tgt) etgt = eo;
    }
    const float inv = 1.0f / S;              // = max(p)
    float S2 = 0.0f;
#pragma unroll
    for (int o = 0; o < O_; ++o) S2 += expf(expf(acc[o] - m) * inv - inv);
    lossc = (inv + logf(S2) - etgt * inv) * (1.0f / (float)B_);
    corr = (pred == tgt) ? 1.0f : 0.0f;
  }
  if (lane == 0) { sl[widx] = lossc; sc[widx] = corr; }
  __syncthreads();
  if (threadIdx.x == 0) {
    partials[blockIdx.x]       = sl[0] + sl[1] + sl[2] + sl[3];
    partials[NB_ + blockIdx.x] = sc[0] + sc[1] + sc[2] + sc[3];
  }
}

__global__ __launch_bounds__(256) void loss_final(
    const float* __restrict__ partials, float* __restrict__ out, float samples)
{
  float a = 0.0f, c = 0.0f;
  for (int i = threadIdx.x; i < NB_; i += 256) { a += partials[i]; c += partials[NB_ + i]; }
  __shared__ float sl[256], sc[256];
  sl[threadIdx.x] = a; sc[threadIdx.x] = c;
  __syncthreads();
  for (int s = 128; s > 0; s >>= 1) {
    if (threadIdx.x < s) {
      sl[threadIdx.x] += sl[threadIdx.x + s];
      sc[threadIdx.x] += sc[threadIdx.x + s];
    }
    __syncthreads();
  }
  if (threadIdx.x == 0) {
    out[0] = sl[0];
    out[1 + (size_t)M_ * O_] = sc[0];
    out[2 + (size_t)M_ * O_] = samples;
  }
}

extern "C" void kernel_launch(void* const* d_in, const int* in_sizes, int n_in,
                              void* d_out, int out_size, void* d_ws, size_t ws_size,
                              hipStream_t stream) {
  const float* input  = (const float*)d_in[0];
  const int*   target = (const int*)d_in[1];
  const float* v_init = (const float*)d_in[2];
  const float* W1     = (const float*)d_in[3];
  const float* W2     = (const float*)d_in[4];
  const float* tau_n  = (const float*)d_in[5];
  const float* tau_m  = (const float*)d_in[6];
  const float* Wout   = (const float*)d_in[7];
  const float* bout   = (const float*)d_in[8];
  float* out = (float*)d_out;
  float* oh  = out + 1;

  // ws: Wb[720896B] drg[500*2*512*116] spkw[500*100*8 u64] partials[2*NB_]
  unsigned short* Wb = (unsigned short*)d_ws;
  unsigned char* drg = (unsigned char*)(Wb + (size_t)2 * H_ * KP_);
  unsigned long long* spkw =
      (unsigned long long*)(drg + (size_t)B_ * 2 * H_ * DRS_);
  float* partials = (float*)(spkw + (size_t)B_ * T_ * 8);

  hipLaunchKernelGGL(convert_w, dim3((2 * H_ * KP_ / 8) / 256), dim3(256), 0, stream,
                     W1, W2, Wb);

  hipLaunchKernelGGL(drive_gemm, dim3(B_), dim3(1024), 0, stream, input, Wb, drg);

  hipLaunchKernelGGL(scan_kernel, dim3(B_), dim3(512), 0, stream,
                     drg, v_init, tau_n, tau_m, spkw);

  hipLaunchKernelGGL(out_loss, dim3(NB_), dim3(256), 0, stream,
                     spkw, Wout, bout, target, oh, partials);

  int mcount = 0;
  for (int t = 0; t < T_; ++t)
    if (t > START_T && ((t - START_T) % (CODING_T + REMAIN_T)) > REMAIN_T) mcount++;
  hipLaunchKernelGGL(loss_final, dim3(1), dim3(256), 0, stream, partials,
                     out, (float)(mcount * B_));
}